// Round 4
// baseline (1014.879 us; speedup 1.0000x reference)
//
#include <hip/hip_runtime.h>
#include <math.h>
#include <stddef.h>

#define L9   9
#define NB   2
#define CF   1024
#define HW   400     // 20*20
#define CH   256
#define TEMPF 20.0f
#define EPSF  1e-12f

typedef _Float16 half8 __attribute__((ext_vector_type(8)));
typedef float f32x4 __attribute__((ext_vector_type(4)));
typedef unsigned short ushort_t;

// ---------------------------------------------------------------------------
// Kernel 1: partial sums of squares over C for l2norm of fq_feats / fs_feats.
// ---------------------------------------------------------------------------
__global__ __launch_bounds__(256) void norm_partial(const float* __restrict__ fq,
                                                    const float* __restrict__ fs,
                                                    float* __restrict__ partial) {
    int t = blockIdx.y;
    int lb = blockIdx.x >> 3;
    int chunk = blockIdx.x & 7;
    const float* src = (t == 0 ? fq : fs) + (size_t)lb * CF * HW;
    int c0 = chunk * 128;
    int tid = threadIdx.x;
    float acc0 = 0.f, acc1 = 0.f;
    for (int c = c0; c < c0 + 128; ++c) {
        const float* row = src + (size_t)c * HW;
        float v0 = row[tid];
        acc0 = fmaf(v0, v0, acc0);
        if (tid < HW - 256) { float v1 = row[tid + 256]; acc1 = fmaf(v1, v1, acc1); }
    }
    float* dst = partial + ((size_t)(t * 18 + lb) * 8 + chunk) * HW;
    dst[tid] = acc0;
    if (tid < HW - 256) dst[tid + 256] = acc1;
}

// ---------------------------------------------------------------------------
// Kernel 2: finalize inverse norms.
// ---------------------------------------------------------------------------
__global__ __launch_bounds__(256) void norm_finalize(const float* __restrict__ partial,
                                                     float* __restrict__ invn) {
    int idx = blockIdx.x * 256 + threadIdx.x;
    if (idx >= 2 * 18 * HW) return;
    int t_lb = idx / HW;
    int ij = idx - t_lb * HW;
    const float* p = partial + (size_t)t_lb * 8 * HW + ij;
    float ss = 0.f;
    #pragma unroll
    for (int c = 0; c < 8; ++c) ss += p[c * HW];
    invn[idx] = 1.0f / fmaxf(sqrtf(ss), EPSF);
}

// ---------------------------------------------------------------------------
// Kernel 3a: transpose+convert: fq[lb][c][ij] -> At[li][ij][c] fp16 (ditto fs->Bt)
// grid (16 ctiles, 7 ijtiles, 18 = tsel*9+li), block 256
// ---------------------------------------------------------------------------
__global__ __launch_bounds__(256) void transpose_f16(const float* __restrict__ fq,
                                                     const float* __restrict__ fs,
                                                     ushort_t* __restrict__ At,
                                                     ushort_t* __restrict__ Bt,
                                                     int lb_base) {
    __shared__ float tile[64][65];
    int z = blockIdx.z;
    int tsel = z / 9, li = z - tsel * 9;
    int lb = lb_base + li;
    const float* src = (tsel ? fs : fq) + (size_t)lb * CF * HW;
    ushort_t* dst = (tsel ? Bt : At) + (size_t)li * HW * CF;
    int c0 = blockIdx.x * 64, ij0 = blockIdx.y * 64;
    int tid = threadIdx.x;
    int cl = tid >> 6;      // 0..3
    int col = tid & 63;
    #pragma unroll
    for (int rr = 0; rr < 16; ++rr) {
        int c_local = rr * 4 + cl;
        int ij = ij0 + col;
        tile[c_local][col] = (ij < HW) ? src[(size_t)(c0 + c_local) * HW + ij] : 0.f;
    }
    __syncthreads();
    int cp = (tid & 31) * 2;
    int rowsel = tid >> 5;  // 0..7
    #pragma unroll
    for (int rr = 0; rr < 8; ++rr) {
        int ij_local = rr * 8 + rowsel;
        int ij = ij0 + ij_local;
        if (ij < HW) {
            union { _Float16 h; ushort_t u; } h0, h1;
            h0.h = (_Float16)tile[cp][ij_local];
            h1.h = (_Float16)tile[cp + 1][ij_local];
            ushort2 o; o.x = h0.u; o.y = h1.u;
            *(ushort2*)(dst + (size_t)ij * CF + c0 + cp) = o;
        }
    }
}

// ---------------------------------------------------------------------------
// Kernel 3b: MFMA fp16 correlation GEMM.
// C[ij][km] = invq[ij]*invs[km] * sum_c At[ij][c]*Bt[km][c]
// block 256 = 4 waves; block tile 64x64; wave tile 32x32 (2x2 16x16 frags).
// grid (7 ntiles, 7 mtiles, 9 li)
// ---------------------------------------------------------------------------
__global__ __launch_bounds__(256) void corr_gemm_mfma(const ushort_t* __restrict__ At,
                                                      const ushort_t* __restrict__ Bt,
                                                      const float* __restrict__ invn,
                                                      float* __restrict__ corr,
                                                      int lb_base) {
    __shared__ ushort_t As[64][72];   // pad k-dim by 8 -> stride 144B
    __shared__ ushort_t Bs[64][72];
    int li = blockIdx.z, lb = lb_base + li;
    int l = lb >> 1, b = lb & 1;
    int i0 = blockIdx.y * 64, j0 = blockIdx.x * 64;
    int tid = threadIdx.x, lane = tid & 63, w = tid >> 6;
    int mw = (w >> 1) * 32, nw = (w & 1) * 32;
    f32x4 acc[2][2] = {};
    const ushort_t* Abase = At + (size_t)li * HW * CF;
    const ushort_t* Bbase = Bt + (size_t)li * HW * CF;

    for (int kt = 0; kt < 16; ++kt) {
        int c0 = kt * 64;
        __syncthreads();
        #pragma unroll
        for (int p = 0; p < 2; ++p) {
            int idx = tid + p * 256;          // 0..511
            int row = idx >> 3, c8 = idx & 7;
            uint4 va = make_uint4(0, 0, 0, 0), vb = make_uint4(0, 0, 0, 0);
            if (i0 + row < HW) va = *(const uint4*)(Abase + (size_t)(i0 + row) * CF + c0 + c8 * 8);
            if (j0 + row < HW) vb = *(const uint4*)(Bbase + (size_t)(j0 + row) * CF + c0 + c8 * 8);
            *(uint4*)&As[row][c8 * 8] = va;
            *(uint4*)&Bs[row][c8 * 8] = vb;
        }
        __syncthreads();
        #pragma unroll
        for (int ks = 0; ks < 2; ++ks) {
            int k0 = ks * 32 + (lane >> 4) * 8;
            half8 a0 = *(const half8*)&As[mw + (lane & 15)][k0];
            half8 a1 = *(const half8*)&As[mw + 16 + (lane & 15)][k0];
            half8 b0 = *(const half8*)&Bs[nw + (lane & 15)][k0];
            half8 b1 = *(const half8*)&Bs[nw + 16 + (lane & 15)][k0];
            acc[0][0] = __builtin_amdgcn_mfma_f32_16x16x32_f16(a0, b0, acc[0][0], 0, 0, 0);
            acc[0][1] = __builtin_amdgcn_mfma_f32_16x16x32_f16(a0, b1, acc[0][1], 0, 0, 0);
            acc[1][0] = __builtin_amdgcn_mfma_f32_16x16x32_f16(a1, b0, acc[1][0], 0, 0, 0);
            acc[1][1] = __builtin_amdgcn_mfma_f32_16x16x32_f16(a1, b1, acc[1][1], 0, 0, 0);
        }
    }
    int obase = (b * 9 + l) * HW;
    #pragma unroll
    for (int mi = 0; mi < 2; ++mi) {
        #pragma unroll
        for (int ni = 0; ni < 2; ++ni) {
            #pragma unroll
            for (int r = 0; r < 4; ++r) {
                int ij = i0 + mw + mi * 16 + (lane >> 4) * 4 + r;   // C/D: row=(lane>>4)*4+reg
                int km = j0 + nw + ni * 16 + (lane & 15);           //      col=lane&15
                if (ij < HW && km < HW)
                    corr[(size_t)(obase + ij) * HW + km] =
                        acc[mi][ni][r] * invn[lb * HW + ij] * invn[7200 + lb * HW + km];
            }
        }
    }
}

// ---------------------------------------------------------------------------
// Kernel 4 (v3): 4D conv + ReLU, register-staged double-buffered LDS.
// ---------------------------------------------------------------------------
template <int CIN, int COUT, bool SWAP, bool ACCUM>
__global__ __launch_bounds__(256) void conv4d_v3(const float* __restrict__ in,
                                                 const float* __restrict__ wt,
                                                 float* __restrict__ out) {
    __shared__ float planes[2][9][22][28];   // 44,352 B
    const int BUFSZ = 9 * 22 * 28;           // 5544 floats
    const int b  = blockIdx.y;
    const int ij = blockIdx.x;
    const int i = ij / 20, j = ij - (ij / 20) * 20;
    const int tid = threadIdx.x;

    float* flat = &planes[0][0][0][0];
    for (int p = tid; p < 2 * BUFSZ; p += 256) flat[p] = 0.f;

    const bool worker = tid < 200;
    const int k = tid / 10;
    const int g = tid - k * 10;

    float acc[COUT][2];
    #pragma unroll
    for (int co = 0; co < COUT; ++co) { acc[co][0] = 0.f; acc[co][1] = 0.f; }

    const float* in_b = in + (size_t)b * CIN * HW * HW;

    int s_gofs[4], s_lofs[4];
    bool s_ok[4];
    #pragma unroll
    for (int p = 0; p < 4; ++p) {
        int slot = tid + p * 256;
        bool valid = slot < 900;
        int pl = slot / 100, e = slot - pl * 100;
        int di = pl / 3, dj = pl - di * 3;
        int ii = i + di - 1, jj = j + dj - 1;
        s_ok[p] = valid && (unsigned)ii < 20u && (unsigned)jj < 20u;
        s_gofs[p] = (ii * 20 + jj) * HW + e * 4;
        int kk = e / 5, c4 = e - kk * 5;
        s_lofs[p] = (pl * 22 + kk + 1) * 28 + 4 + 4 * c4;
    }
    __syncthreads();   // zeroing complete

    // prestage cin 0 into buffer 0
    {
        float4 rs[4];
        #pragma unroll
        for (int p = 0; p < 4; ++p) if (s_ok[p]) rs[p] = *(const float4*)(in_b + s_gofs[p]);
        #pragma unroll
        for (int p = 0; p < 4; ++p) if (s_ok[p]) *(float4*)(flat + s_lofs[p]) = rs[p];
    }

    #pragma unroll 1
    for (int cin = 0; cin < CIN; ++cin) {
        __syncthreads();
        const int cur = cin & 1;
        const bool pre = (cin + 1) < CIN;
        float4 rs[4];
        if (pre) {
            const float* ic = in_b + (size_t)(cin + 1) * HW * HW;
            #pragma unroll
            for (int p = 0; p < 4; ++p) if (s_ok[p]) rs[p] = *(const float4*)(ic + s_gofs[p]);
        }
        if (worker) {
            const float (*P)[22][28] = planes[cur];
            #pragma unroll 1
            for (int pl = 0; pl < 9; ++pl) {
                float vv[3][4];
                #pragma unroll
                for (int dk = 0; dk < 3; ++dk) {
                    const float* rowp = &P[pl][k + dk][3 + 2 * g];
                    vv[dk][0] = rowp[0]; vv[dk][1] = rowp[1];
                    vv[dk][2] = rowp[2]; vv[dk][3] = rowp[3];
                }
                #pragma unroll
                for (int co = 0; co < COUT; ++co) {
                    const int base = (co * CIN + cin) * 81;
                    #pragma unroll
                    for (int dd = 0; dd < 9; ++dd) {
                        const int dk = dd / 3, dm = dd % 3;
                        const float w = SWAP ? wt[base + dd * 9 + pl]
                                             : wt[base + pl * 9 + dd];
                        acc[co][0] = fmaf(w, vv[dk][dm],     acc[co][0]);
                        acc[co][1] = fmaf(w, vv[dk][dm + 1], acc[co][1]);
                    }
                }
            }
        }
        if (pre) {
            float* dstf = flat + (1 - cur) * BUFSZ;
            #pragma unroll
            for (int p = 0; p < 4; ++p) if (s_ok[p]) *(float4*)(dstf + s_lofs[p]) = rs[p];
        }
    }

    if (worker) {
        const int km = k * 20 + 2 * g;
        #pragma unroll
        for (int co = 0; co < COUT; ++co) {
            float r0 = fmaxf(acc[co][0], 0.f);
            float r1 = fmaxf(acc[co][1], 0.f);
            size_t o = ((size_t)(b * COUT + co) * HW + ij) * HW + km;
            if (ACCUM) { out[o] += r0; out[o + 1] += r1; }
            else { float2 v = make_float2(r0, r1); *(float2*)(out + o) = v; }
        }
    }
}

// ---------------------------------------------------------------------------
// Kernel 5: softmax over s + att_fq = attn . V
// ---------------------------------------------------------------------------
__global__ __launch_bounds__(256) void softmax_av(const float* __restrict__ c4,
                                                  const float* __restrict__ f_s,
                                                  float* __restrict__ att_out) {
    __shared__ float p[HW];
    __shared__ float red[256];
    int b = blockIdx.y, q = blockIdx.x;
    int tid = threadIdx.x;
    const float* row = c4 + ((size_t)b * HW + q) * HW;
    float v0 = row[tid] * TEMPF;
    float v1 = (tid < HW - 256) ? row[tid + 256] * TEMPF : -1e30f;
    red[tid] = fmaxf(v0, v1);
    __syncthreads();
    for (int s = 128; s > 0; s >>= 1) {
        if (tid < s) red[tid] = fmaxf(red[tid], red[tid + s]);
        __syncthreads();
    }
    float mx = red[0];
    __syncthreads();
    float e0 = expf(v0 - mx);
    float e1 = (tid < HW - 256) ? expf(v1 - mx) : 0.f;
    p[tid] = e0;
    if (tid < HW - 256) p[tid + 256] = e1;
    red[tid] = e0 + e1;
    __syncthreads();
    for (int s = 128; s > 0; s >>= 1) {
        if (tid < s) red[tid] += red[tid + s];
        __syncthreads();
    }
    float inv = 1.0f / red[0];
    const float* vrow = f_s + (size_t)(b * CH + tid) * HW;
    float acc = 0.f;
    for (int s = 0; s < HW; ++s) acc = fmaf(p[s], vrow[s], acc);
    att_out[(size_t)(b * CH + tid) * HW + q] = acc * inv;
}

// ---------------------------------------------------------------------------
// Kernel 6: fq = l2norm(f_q, ch) + 0.5 * l2norm(att_fq, ch)
// ---------------------------------------------------------------------------
__global__ __launch_bounds__(256) void final_fq(const float* __restrict__ f_q,
                                                const float* __restrict__ att,
                                                float* __restrict__ out_fq) {
    __shared__ float red[256];
    int b = blockIdx.y, q = blockIdx.x;
    int tid = threadIdx.x;
    size_t idx = (size_t)(b * CH + tid) * HW + q;
    float f = f_q[idx];
    float a = att[idx];
    red[tid] = f * f;
    __syncthreads();
    for (int s = 128; s > 0; s >>= 1) {
        if (tid < s) red[tid] += red[tid + s];
        __syncthreads();
    }
    float invf = 1.0f / fmaxf(sqrtf(red[0]), EPSF);
    __syncthreads();
    red[tid] = a * a;
    __syncthreads();
    for (int s = 128; s > 0; s >>= 1) {
        if (tid < s) red[tid] += red[tid + s];
        __syncthreads();
    }
    float inva = 1.0f / fmaxf(sqrtf(red[0]), EPSF);
    out_fq[idx] = f * invf + 0.5f * a * inva;
}

// ---------------------------------------------------------------------------
extern "C" void kernel_launch(void* const* d_in, const int* in_sizes, int n_in,
                              void* d_out, int out_size, void* d_ws, size_t ws_size,
                              hipStream_t stream) {
    const float* fq_feats = (const float*)d_in[0];
    const float* fs_feats = (const float*)d_in[1];
    const float* f_q      = (const float*)d_in[2];
    const float* f_s      = (const float*)d_in[3];
    const float* w1       = (const float*)d_in[4];
    const float* w2       = (const float*)d_in[5];
    const float* w3       = (const float*)d_in[6];
    float* out = (float*)d_out;              // fq at 0, att_fq at 204800

    float* ws      = (float*)d_ws;
    float* partial = ws;                     // 115,200
    float* invn    = partial + 115200;       // 14,400
    float* corr    = invn + 14400;           // 2,880,000
    float* buf1    = corr + 2880000;         // 3,200,000
    float* buf2    = buf1 + 3200000;         // 3,200,000
    float* c4      = buf2 + 3200000;         // 320,000
    float* att     = out + 204800;

    // fp16 transposed copies overlay buf1/buf2 (7.37 MB each into 12.8 MB slots)
    ushort_t* At = (ushort_t*)buf1;
    ushort_t* Bt = (ushort_t*)buf2;

    norm_partial<<<dim3(18 * 8, 2), 256, 0, stream>>>(fq_feats, fs_feats, partial);
    norm_finalize<<<(2 * 18 * HW + 255) / 256, 256, 0, stream>>>(partial, invn);

    // correlation GEMM in two l-batches of 9 (buffers reused)
    for (int half = 0; half < 2; ++half) {
        int base = half * 9;
        transpose_f16<<<dim3(16, 7, 18), 256, 0, stream>>>(fq_feats, fs_feats, At, Bt, base);
        corr_gemm_mfma<<<dim3(7, 7, 9), 256, 0, stream>>>(At, Bt, invn, corr, base);
    }

    // path A (identity orientation)
    conv4d_v3<9, 10, false, false><<<dim3(400, NB), 256, 0, stream>>>(corr, w1, buf1);
    conv4d_v3<10, 10, false, false><<<dim3(400, NB), 256, 0, stream>>>(buf1, w2, buf2);
    conv4d_v3<10, 1, false, false><<<dim3(400, NB), 256, 0, stream>>>(buf2, w3, c4);
    // path B (transposed path folded via tap-swapped weights)
    conv4d_v3<9, 10, true, false><<<dim3(400, NB), 256, 0, stream>>>(corr, w1, buf1);
    conv4d_v3<10, 10, true, false><<<dim3(400, NB), 256, 0, stream>>>(buf1, w2, buf2);
    conv4d_v3<10, 1, true, true><<<dim3(400, NB), 256, 0, stream>>>(buf2, w3, c4);

    softmax_av<<<dim3(400, NB), 256, 0, stream>>>(c4, f_s, att);
    final_fq<<<dim3(400, NB), 256, 0, stream>>>(f_q, att, out);

    (void)in_sizes; (void)n_in; (void)out_size; (void)ws_size;
}